// Round 1
// baseline (204.646 us; speedup 1.0000x reference)
//
#include <hip/hip_runtime.h>

// XCorrExt: B=32, S=160000, N=320, H=160, TAU=257, LAG_CUT=33
// out[b,f,tau-33] = 2*num/(e0 + e_tau + 1e-5), tau in [33,256]
// num[b,f,tau] = sum_n ext[tau+n]*frame[n]; frame[n] = xp[160f+n]
// ext[t] = xp[160f+t] (t<320) | xp[160f+t-160] (t>=320) | f=999,t>=320: x[t-320]
//
// R5: two stall-removal fixes.
// (a) Spills: R4's amdgpu_waves_per_eu(4,4) never took effect (VGPR_Count
//     stayed 64 with ~80 live -> in-loop scratch, +7.5MB WRITE_SIZE).
//     __launch_bounds__(256, 4) is the documented route to a 128-VGPR
//     budget while guaranteeing 4 blocks/CU (grid is exactly 4/CU).
// (b) LDS conflicts: W-prefetch addr = 164g+28r+t == 4(g-r) mod 32 ->
//     8-way bank-quad aliasing, ~32 extra cyc per ds_read_b128 (matches
//     the 1.07e7 SQ_LDS_BANK_CONFLICT). Linear padding cannot fix a
//     (g-r) collapse; XOR-swizzle bank-quad bits with row bits:
//     swz(a) = a ^ ((((a>>5)^(a>>8))&7)<<2). Bijective, keeps quads
//     contiguous & 16B-aligned, applied to ALL lds accesses.

#define S_LEN 160000
#define FN    1000
#define NF    32
#define BLOCK 256
#define XSZ   (160 * (NF - 1) + 480)   // 5440 logical floats of signal
#define PHYS(i) ((i) + 4 * ((i) / 160))
#define TOFF  5576                     // > PHYS(XSZ-1)+3, multiple of 4
#define LDSZ  5856                     // row-of-32 aligned so swz stays in-bounds

__device__ __forceinline__ int swz(int a) {
    return a ^ ((((a >> 5) ^ (a >> 8)) & 7) << 2);
}

__global__ __launch_bounds__(BLOCK, 4)
void xcorr_kernel(const float* __restrict__ x, float* __restrict__ out) {
    __shared__ __align__(16) float lds[LDSZ];
    const int tid   = threadIdx.x;
    const int b     = blockIdx.y;
    const int fbase = blockIdx.x * NF;
    const long bOff = (long)b * S_LEN;
    const int gbase = fbase * 160;

    // ---------------- stage shared X, swizzled (coalesced float4 reads) --------
    for (int i = 4 * tid; i < XSZ; i += 4 * BLOCK) {
        const int gx = gbase + i;
        const int pa = swz(PHYS(i));   // quads never cross a 160-region (4|160)
        if (gx + 3 < S_LEN) {
            *(float4*)&lds[pa] = *(const float4*)&x[bOff + gx];
        } else {
#pragma unroll
            for (int e = 0; e < 4; ++e)
                lds[pa + e] = (gx + e < S_LEN) ? x[bOff + gx + e] : 0.f;
        }
    }
    // T[j] = ext_{999}[320+j] = x[b, j]  (only the block containing f=999)
    if (fbase + NF > FN - 1) {
        for (int j = tid; j < 264; j += BLOCK)
            lds[swz(TOFF + j)] = x[bOff + j];
    }
    __syncthreads();

    // ---------------- compute ----------------
    const int g    = tid >> 3;         // frame group 0..31
    const int r    = tid & 7;          // lane in group
    const int f    = fbase + g;
    const bool useT = (f == FN - 1);
    const int tau0 = 33 + 28 * r;
    const int wb   = tau0 - 1;         // 32+28r, multiple of 4
    const int xg   = 164 * g;          // region-padded group base (160g + 4g)
    // ext addr = w + C, C selected by w-range (fold + region pad folded in):
    const int C0 = xg;                                // w in [0,160)
    const int C1 = xg + 4;                            // w in [160,320)
    const int C2 = useT ? (TOFF - 320) : (xg - 156);  // w in [320,480)
    const int C3 = useT ? (TOFF - 320) : (xg - 152);  // w in [480,580)

    float acc[28];
#pragma unroll
    for (int c = 0; c < 28; ++c) acc[c] = 0.f;
    float W[32];       // rotating window: ext[wb + o] at slot o & 31
    float FQ[2][4];    // rotating frame quad (distance-2 prefetch)

#pragma unroll
    for (int j = 0; j < 8; ++j) {      // w = wb..wb+31 <= 259 < 320: C0/C1 only
        const int w = wb + 4 * j;
        const float4 q = *(const float4*)&lds[swz(w + ((w < 160) ? C0 : C1))];
        W[4*j] = q.x; W[4*j+1] = q.y; W[4*j+2] = q.z; W[4*j+3] = q.w;
    }
#pragma unroll
    for (int j = 0; j < 2; ++j) {      // frame quads 0,1 (region 0)
        const float4 q = *(const float4*)&lds[swz(xg + 4 * j)];
        FQ[j][0] = q.x; FQ[j][1] = q.y; FQ[j][2] = q.z; FQ[j][3] = q.w;
    }

    float Tsum = 0.f, e0 = 0.f;

#pragma unroll 1
    for (int ko = 0; ko < 10; ++ko) {
#pragma unroll
        for (int ki = 0; ki < 8; ++ki) {
            const int k = ko * 8 + ki;
#pragma unroll
            for (int d = 0; d < 4; ++d) {
                const float fv = FQ[ki & 1][d];
#pragma unroll
                for (int c = 0; c < 28; ++c)
                    acc[c] = fmaf(fv, W[(1 + 4 * ki + d + c) & 31], acc[c]);
                const float tv = W[(1 + 4 * ki + d) & 31];   // ext[tau0+4k+d]
                Tsum = fmaf(tv, tv, Tsum);                   // offsets 1..320
                e0   = fmaf(fv, fv, e0);                     // frame energy
            }
            // prefetch ext quad k+8 (w = wb+4k+32 .. +3, slots (4ki..4ki+3)&31)
            {
                const int w = wb + 4 * k + 32;
                const int cc = (w < 160) ? C0 : (w < 320) ? C1 : (w < 480) ? C2 : C3;
                const float4 q = *(const float4*)&lds[swz(w + cc)];
                W[(4*ki + 0) & 31] = q.x; W[(4*ki + 1) & 31] = q.y;
                W[(4*ki + 2) & 31] = q.z; W[(4*ki + 3) & 31] = q.w;
            }
            // prefetch frame quad k+2 into slot (k+2)&1 == ki&1 (used round k+2)
            {
                const int fo = 4 * k + 8;
                const float4 q = *(const float4*)&lds[swz(xg + fo + 4 * (fo / 160))];
                FQ[ki & 1][0] = q.x; FQ[ki & 1][1] = q.y;
                FQ[ki & 1][2] = q.z; FQ[ki & 1][3] = q.w;
            }
        }
    }

    // ---------------- epilogue: e_tau chain + normalize, chunked stores -------
    if (f < FN) {
        float* op = &out[((long)(b * FN + f)) * 224 + 28 * r];
        float et = Tsum;               // e_tau[tau0]
#pragma unroll
        for (int q = 0; q < 7; ++q) {
            float res[4];
#pragma unroll
            for (int e = 0; e < 4; ++e) {
                const int c = 4 * q + e;
                const float den = e0 + et + 1e-5f;
                res[e] = 2.f * acc[c] * __builtin_amdgcn_rcpf(den);
                if (c < 27) {
                    const int u = tau0 + c;                   // ext[u], u < 320
                    const float pv = lds[swz(xg + u + ((u >= 160) ? 4 : 0))];
                    const int v = u + 160;                    // fold of ext[u+320]
                    const float sv = useT ? lds[swz(TOFF + u)]
                                          : lds[swz(xg + v + ((v >= 320) ? 8 : 4))];
                    et += sv * sv - pv * pv;
                }
            }
            *(float4*)&op[4 * q] = make_float4(res[0], res[1], res[2], res[3]);
        }
    }
}

extern "C" void kernel_launch(void* const* d_in, const int* in_sizes, int n_in,
                              void* d_out, int out_size, void* d_ws, size_t ws_size,
                              hipStream_t stream) {
    const float* x = (const float*)d_in[0];
    float* out = (float*)d_out;
    dim3 grid((FN + NF - 1) / NF, 32);   // (32, 32) = 1024 blocks = 4 per CU
    dim3 block(BLOCK);
    hipLaunchKernelGGL(xcorr_kernel, grid, block, 0, stream, x, out);
}

// Round 2
// 179.326 us; speedup vs baseline: 1.1412x; 1.1412x over previous
//
#include <hip/hip_runtime.h>

// XCorrExt: B=32, S=160000, N=320, H=160, TAU=257, LAG_CUT=33
// out[b,f,tau-33] = 2*num/(e0 + e_tau + 1e-5), tau in [33,256]
// num[b,f,tau] = sum_n ext[tau+n]*frame[n]; frame[n] = xp[160f+n]
// ext[t] = xp[160f+t] (t<320) | xp[160f+t-160] (t>=320) | f=999,t>=320: x[t-320]
//
// R6: exact R4 structure (78us dispatch) + CORRECT bank-conflict swizzle.
// R5 post-mortem: (a) launch_bounds(256,4) wrecked spill codegen
// (WRITE_SIZE 36->500MB) -> reverted to amdgpu_waves_per_eu(4,4);
// (b) the ((a>>5)^(a>>8)) swizzle was wrong: W-conflict lanes differ by
// 192*delta, and (192d)>>5 = 6d mod 8 hits only {0,2,4,6} -> conflicts
// ROSE to 2.5e7, and it broke the conflict-free FQ broadcasts.
// Correct fix: (192d)>>6 = 3d exactly (192 has zero low-6 bits) and
// 3d mod 8 is a bijection -> XOR bank-quad bits (2..4) with bits 6..8:
//   swz(a) = a ^ ((a>>4) & 28)
// W/epilogue 8-way classes -> 8 distinct quads (wrapped lanes <=2-way,
// free); FQ broadcasts stay <=2-way; staging writes stay conflict-free;
// quads remain contiguous + 16B-aligned (only bits 2..4 change, from
// bits >=6, addresses 4-aligned).

#define S_LEN 160000
#define FN    1000
#define NF    32
#define BLOCK 256
#define XSZ   (160 * (NF - 1) + 480)   // 5440 logical floats of signal
#define PHYS(i) ((i) + 4 * ((i) / 160))
#define TOFF  5576                     // > PHYS(XSZ-1)+3, multiple of 4
#define LDSZ  5856                     // covers swz range: max swz(5839) <= 5855

__device__ __forceinline__ int swz(int a) {
    return a ^ ((a >> 4) & 28);        // XOR quad bits 2..4 with bits 6..8
}

__global__ __launch_bounds__(BLOCK)
__attribute__((amdgpu_waves_per_eu(4, 4)))
void xcorr_kernel(const float* __restrict__ x, float* __restrict__ out) {
    __shared__ __align__(16) float lds[LDSZ];
    const int tid   = threadIdx.x;
    const int b     = blockIdx.y;
    const int fbase = blockIdx.x * NF;
    const long bOff = (long)b * S_LEN;
    const int gbase = fbase * 160;

    // ---------------- stage shared X, swizzled (coalesced float4 reads) --------
    for (int i = 4 * tid; i < XSZ; i += 4 * BLOCK) {
        const int gx = gbase + i;
        const int pa = swz(PHYS(i));   // quads never cross a 160-region (4|160)
        if (gx + 3 < S_LEN) {
            *(float4*)&lds[pa] = *(const float4*)&x[bOff + gx];
        } else {
#pragma unroll
            for (int e = 0; e < 4; ++e)
                lds[pa + e] = (gx + e < S_LEN) ? x[bOff + gx + e] : 0.f;
        }
    }
    // T[j] = ext_{999}[320+j] = x[b, j]  (only the block containing f=999)
    if (fbase + NF > FN - 1) {
        for (int j = tid; j < 264; j += BLOCK)
            lds[swz(TOFF + j)] = x[bOff + j];
    }
    __syncthreads();

    // ---------------- compute ----------------
    const int g    = tid >> 3;         // frame group 0..31
    const int r    = tid & 7;          // lane in group
    const int f    = fbase + g;
    const bool useT = (f == FN - 1);
    const int tau0 = 33 + 28 * r;
    const int wb   = tau0 - 1;         // 32+28r, multiple of 4
    const int xg   = 164 * g;          // region-padded group base (160g + 4g)
    // ext addr = w + C, C selected by w-range (fold + region pad folded in):
    const int C0 = xg;                                // w in [0,160)
    const int C1 = xg + 4;                            // w in [160,320)
    const int C2 = useT ? (TOFF - 320) : (xg - 156);  // w in [320,480)
    const int C3 = useT ? (TOFF - 320) : (xg - 152);  // w in [480,580)

    float acc[28];
#pragma unroll
    for (int c = 0; c < 28; ++c) acc[c] = 0.f;
    float W[32];       // rotating window: ext[wb + o] at slot o & 31
    float FQ[2][4];    // rotating frame quad (distance-2 prefetch)

#pragma unroll
    for (int j = 0; j < 8; ++j) {      // w = wb..wb+31 <= 259 < 320: C0/C1 only
        const int w = wb + 4 * j;
        const float4 q = *(const float4*)&lds[swz(w + ((w < 160) ? C0 : C1))];
        W[4*j] = q.x; W[4*j+1] = q.y; W[4*j+2] = q.z; W[4*j+3] = q.w;
    }
#pragma unroll
    for (int j = 0; j < 2; ++j) {      // frame quads 0,1 (region 0)
        const float4 q = *(const float4*)&lds[swz(xg + 4 * j)];
        FQ[j][0] = q.x; FQ[j][1] = q.y; FQ[j][2] = q.z; FQ[j][3] = q.w;
    }

    float Tsum = 0.f, e0 = 0.f;

#pragma unroll 1
    for (int ko = 0; ko < 10; ++ko) {
#pragma unroll
        for (int ki = 0; ki < 8; ++ki) {
            const int k = ko * 8 + ki;
#pragma unroll
            for (int d = 0; d < 4; ++d) {
                const float fv = FQ[ki & 1][d];
#pragma unroll
                for (int c = 0; c < 28; ++c)
                    acc[c] = fmaf(fv, W[(1 + 4 * ki + d + c) & 31], acc[c]);
                const float tv = W[(1 + 4 * ki + d) & 31];   // ext[tau0+4k+d]
                Tsum = fmaf(tv, tv, Tsum);                   // offsets 1..320
                e0   = fmaf(fv, fv, e0);                     // frame energy
            }
            // prefetch ext quad k+8 (w = wb+4k+32 .. +3, slots (4ki..4ki+3)&31)
            {
                const int w = wb + 4 * k + 32;
                const int cc = (w < 160) ? C0 : (w < 320) ? C1 : (w < 480) ? C2 : C3;
                const float4 q = *(const float4*)&lds[swz(w + cc)];
                W[(4*ki + 0) & 31] = q.x; W[(4*ki + 1) & 31] = q.y;
                W[(4*ki + 2) & 31] = q.z; W[(4*ki + 3) & 31] = q.w;
            }
            // prefetch frame quad k+2 into slot (k+2)&1 == ki&1 (used round k+2)
            {
                const int fo = 4 * k + 8;
                const float4 q = *(const float4*)&lds[swz(xg + fo + 4 * (fo / 160))];
                FQ[ki & 1][0] = q.x; FQ[ki & 1][1] = q.y;
                FQ[ki & 1][2] = q.z; FQ[ki & 1][3] = q.w;
            }
        }
    }

    // ---------------- epilogue: e_tau chain + normalize, chunked stores -------
    if (f < FN) {
        float* op = &out[((long)(b * FN + f)) * 224 + 28 * r];
        float et = Tsum;               // e_tau[tau0]
#pragma unroll
        for (int q = 0; q < 7; ++q) {
            float res[4];
#pragma unroll
            for (int e = 0; e < 4; ++e) {
                const int c = 4 * q + e;
                const float den = e0 + et + 1e-5f;
                res[e] = 2.f * acc[c] * __builtin_amdgcn_rcpf(den);
                if (c < 27) {
                    const int u = tau0 + c;                   // ext[u], u < 320
                    const float pv = lds[swz(xg + u + ((u >= 160) ? 4 : 0))];
                    const int v = u + 160;                    // fold of ext[u+320]
                    const float sv = useT ? lds[swz(TOFF + u)]
                                          : lds[swz(xg + v + ((v >= 320) ? 8 : 4))];
                    et += sv * sv - pv * pv;
                }
            }
            *(float4*)&op[4 * q] = make_float4(res[0], res[1], res[2], res[3]);
        }
    }
}

extern "C" void kernel_launch(void* const* d_in, const int* in_sizes, int n_in,
                              void* d_out, int out_size, void* d_ws, size_t ws_size,
                              hipStream_t stream) {
    const float* x = (const float*)d_in[0];
    float* out = (float*)d_out;
    dim3 grid((FN + NF - 1) / NF, 32);   // (32, 32) = 1024 blocks = 4 per CU
    dim3 block(BLOCK);
    hipLaunchKernelGGL(xcorr_kernel, grid, block, 0, stream, x, out);
}

// Round 4
// 132.036 us; speedup vs baseline: 1.5499x; 1.3582x over previous
//
#include <hip/hip_runtime.h>

// XCorrExt: B=32, S=160000, N=320, H=160, TAU=257, LAG_CUT=33
// out[b,f,tau-33] = 2*num/(e0 + e_tau + 1e-5), tau in [33,256]
// num[b,f,tau] = sum_n ext[tau+n]*frame[n]; frame[n] = xp[160f+n]
// ext[t] = xp[160f+t] (t<320) | xp[160f+t-160] (t>=320) | f=999,t>=320: x[t-320]
//
// R8 = R7 resubmitted (container infra failure, no measurement; source
// re-audited: no OOB reads/writes, no divergent barriers, slot invariants
// verified).
// R7: occupancy 4->8 waves/SIMD via k-split. R4 analysis: per-wave stalls
// should be hidden (prefetch distances 8/2) yet VALUBusy=68% -> all 4
// resident waves stall together; grid was hard-capped at 1024 blocks
// (4/CU). Split each frame's k-range across two groups: groups 0-15 do
// k=0..39, groups 16-31 do k=40..79 (same frames), NF=16, grid 63x32 =
// 2016 blocks -> 8 blocks/CU (LDS 19.5KB fits 8). Partial acc/e0/Tsum
// combined via small LDS buffer (stride 13 -> 2-way, free), 3 chunks.
// Epilogue: sv_c == W[1+c] at loop end (window holds ext[wb+320..+351])
// -> kills 27 of 54 8-way-conflicted scalar reads; pv via 8 rolling b128
// quad reads. FQ fo/160 div replaced by 2 compares on k.
// Swizzle attempts (R5/R6) both regressed: reverted, no swz anywhere.

#define S_LEN 160000
#define FN    1000
#define NF    16
#define BLOCK 256
#define XSZ   (160 * (NF - 1) + 480)   // 2880 logical floats of signal
#define PHYS(i) ((i) + 4 * ((i) / 160))
#define TOFF  2948                     // > PHYS(XSZ-1)+3 = 2947, multiple of 4
#define CBO   3212                     // combine buffer (after T region 264)
#define CBSTR 13                       // stride 13: 13L mod 32 -> 2-way, free
#define LDSZ  (CBO + CBSTR * 128)      // 4876 floats = 19.5 KB -> 8 blocks/CU

__global__ __launch_bounds__(BLOCK)
void xcorr_kernel(const float* __restrict__ x, float* __restrict__ out) {
    __shared__ __align__(16) float lds[LDSZ];
    const int tid   = threadIdx.x;
    const int b     = blockIdx.y;
    const int fbase = blockIdx.x * NF;
    const long bOff = (long)b * S_LEN;
    const int gbase = fbase * 160;

    // ---------------- stage shared X (coalesced float4, region-pad layout) ----
    for (int i = 4 * tid; i < XSZ; i += 4 * BLOCK) {
        const int gx = gbase + i;
        const int pa = PHYS(i);        // quads never cross a 160-region (4|160)
        if (gx + 3 < S_LEN) {
            *(float4*)&lds[pa] = *(const float4*)&x[bOff + gx];
        } else {
#pragma unroll
            for (int e = 0; e < 4; ++e)
                lds[pa + e] = (gx + e < S_LEN) ? x[bOff + gx + e] : 0.f;
        }
    }
    // T[j] = ext_{999}[320+j] = x[b, j]  (only the block containing f=999)
    if (fbase + NF > FN - 1) {
        for (int j = tid; j < 264; j += BLOCK)
            lds[TOFF + j] = x[bOff + j];
    }
    __syncthreads();

    // ---------------- compute ----------------
    const int g     = tid >> 3;        // group 0..31
    const int r     = tid & 7;         // lane in group
    const int h     = g & 15;          // frame slot 0..15
    const int half  = g >> 4;          // 0: k=0..39, 1: k=40..79
    const int f     = fbase + h;
    const bool useT = (f == FN - 1);
    const int tau0  = 33 + 28 * r;
    const int wb    = tau0 - 1;        // 32+28r, multiple of 4
    const int xg    = 164 * h;         // region-padded frame base (160h + 4h)
    // ext addr = w + C, C selected by w-range (fold + region pad folded in):
    const int C0 = xg;                                // w in [0,160)
    const int C1 = xg + 4;                            // w in [160,320)
    const int C2 = useT ? (TOFF - 320) : (xg - 156);  // w in [320,480)
    const int C3 = useT ? (TOFF - 320) : (xg - 152);  // w in [480,580)
    const int kbase = half * 40;

    float acc[28];
#pragma unroll
    for (int c = 0; c < 28; ++c) acc[c] = 0.f;
    float W[32];       // rotating window: ext[wb + o] at slot o & 31
    float FQ[2][4];    // rotating frame quad (distance-2 prefetch)

#pragma unroll
    for (int j = 0; j < 8; ++j) {      // window init at this half's k-start
        const int w = wb + 160 * half + 4 * j;   // 160*half ≡ 0 mod 32: slots ok
        const int cc = (w < 160) ? C0 : (w < 320) ? C1 : (w < 480) ? C2 : C3;
        const float4 q = *(const float4*)&lds[w + cc];
        W[4*j] = q.x; W[4*j+1] = q.y; W[4*j+2] = q.z; W[4*j+3] = q.w;
    }
#pragma unroll
    for (int j = 0; j < 2; ++j) {      // frame quads kbase, kbase+1
        const int fo = 4 * (kbase + j);
        const int pad = ((fo >= 160) ? 4 : 0) + ((fo >= 320) ? 4 : 0);
        const float4 q = *(const float4*)&lds[xg + fo + pad];
        FQ[j][0] = q.x; FQ[j][1] = q.y; FQ[j][2] = q.z; FQ[j][3] = q.w;
    }

    float Tsum = 0.f, e0 = 0.f;

#pragma unroll 1
    for (int ko = 0; ko < 5; ++ko) {
#pragma unroll
        for (int ki = 0; ki < 8; ++ki) {
            const int k = kbase + ko * 8 + ki;   // kbase even: k&7 == ki
#pragma unroll
            for (int d = 0; d < 4; ++d) {
                const float fv = FQ[ki & 1][d];
#pragma unroll
                for (int c = 0; c < 28; ++c)
                    acc[c] = fmaf(fv, W[(1 + 4 * ki + d + c) & 31], acc[c]);
                const float tv = W[(1 + 4 * ki + d) & 31];   // ext[tau0+4k+d]
                Tsum = fmaf(tv, tv, Tsum);                   // this half's slice
                e0   = fmaf(fv, fv, e0);                     // frame energy slice
            }
            // prefetch ext quad k+8 (w = wb+4k+32, slots (4ki..4ki+3)&31)
            {
                const int w = wb + 4 * k + 32;
                const int cc = (w < 160) ? C0 : (w < 320) ? C1 : (w < 480) ? C2 : C3;
                const float4 q = *(const float4*)&lds[w + cc];
                W[(4*ki + 0) & 31] = q.x; W[(4*ki + 1) & 31] = q.y;
                W[(4*ki + 2) & 31] = q.z; W[(4*ki + 3) & 31] = q.w;
            }
            // prefetch frame quad k+2 into slot (k+2)&1 == ki&1 (used round k+2)
            {
                const int fo = 4 * k + 8;
                const int pad = ((k >= 38) ? 4 : 0) + ((k >= 78) ? 4 : 0);
                const float4 q = *(const float4*)&lds[xg + fo + pad];
                FQ[ki & 1][0] = q.x; FQ[ki & 1][1] = q.y;
                FQ[ki & 1][2] = q.z; FQ[ki & 1][3] = q.w;
            }
        }
    }

    // ---------------- combine halves: half0 -> LDS -> half1 adds --------------
    // 30 values per lane: acc[0..27], e0, Tsum; 3 chunks of 10.
#pragma unroll
    for (int ch = 0; ch < 3; ++ch) {
        if (half == 0) {
#pragma unroll
            for (int j = 0; j < 10; ++j) {
                const int i = 10 * ch + j;
                const float v = (i < 28) ? acc[i] : ((i == 28) ? e0 : Tsum);
                lds[CBO + CBSTR * tid + j] = v;
            }
        }
        __syncthreads();
        if (half == 1) {
#pragma unroll
            for (int j = 0; j < 10; ++j) {
                const int i = 10 * ch + j;
                const float v = lds[CBO + CBSTR * (tid - 128) + j];
                if (i < 28) acc[i] += v;
                else if (i == 28) e0 += v;
                else Tsum += v;
            }
        }
        __syncthreads();
    }

    // ---------------- epilogue (half1 only): e_tau chain + normalize ----------
    // At half1 loop end, W[s] = ext[wb+320+s]  ->  sv_c = W[1+c] (in regs).
    // pv_c = ext[wb+1+c]: rolling b128 quad reads (8 total, quad-aligned).
    if (half == 1 && f < FN) {
        float* op = &out[((long)(b * FN + f)) * 224 + 28 * r];
        float et = Tsum;               // e_tau[tau0]
        float4 Qa = *(const float4*)&lds[wb + ((wb < 160) ? C0 : C1)];
#pragma unroll
        for (int q = 0; q < 7; ++q) {
            const int wq = wb + 4 * q + 4;           // <= wb+28 <= 256 < 320
            const float4 Qb = *(const float4*)&lds[wq + ((wq < 160) ? C0 : C1)];
            const float pvv[4] = {Qa.y, Qa.z, Qa.w, Qb.x};
            float res[4];
#pragma unroll
            for (int e = 0; e < 4; ++e) {
                const int c = 4 * q + e;
                const float den = e0 + et + 1e-5f;
                res[e] = 2.f * acc[c] * __builtin_amdgcn_rcpf(den);
                if (c < 27) {
                    const float sv = W[1 + c];       // ext[tau0+c+320]
                    const float pv = pvv[e];         // ext[tau0+c]
                    et += sv * sv - pv * pv;
                }
            }
            *(float4*)&op[4 * q] = make_float4(res[0], res[1], res[2], res[3]);
            Qa = Qb;
        }
    }
}

extern "C" void kernel_launch(void* const* d_in, const int* in_sizes, int n_in,
                              void* d_out, int out_size, void* d_ws, size_t ws_size,
                              hipStream_t stream) {
    const float* x = (const float*)d_in[0];
    float* out = (float*)d_out;
    dim3 grid((FN + NF - 1) / NF, 32);   // (63, 32) = 2016 blocks ~ 8 per CU
    dim3 block(BLOCK);
    hipLaunchKernelGGL(xcorr_kernel, grid, block, 0, stream, x, out);
}